// Round 11
// baseline (317.928 us; speedup 1.0000x reference)
//
#include <hip/hip_runtime.h>
#include <hip/hip_bf16.h>

#define TXT   512
#define REDUX 64
#define IMG   2048
#define REFN  512
#define NC    2
#define SEQ   3168
#define DH    128
#define NH    24
#define TRE   576
#define TRI   2624
#define TRIR  3136
#define SCALE 0.08838834764831845f
#define L2E   1.4426950408889634f
#define QSC   (SCALE * L2E)          // scale folded with log2(e)
#define C100  (100.0f * L2E)         // 144.2695
#define CREF  (98.5f * L2E)          // 142.1055
#define THR2  (4.0f * L2E)           // defer-max threshold in log2 units

using f32x4  = __attribute__((ext_vector_type(4))) float;
using short8 = __attribute__((ext_vector_type(8))) short;

__device__ inline short f2bf(float x) {
    union { __hip_bfloat16 b; short s; } u;
    u.b = __float2bfloat16(x);
    return u.s;
}

__device__ inline void gload16(const short* g, short* l) {
    __builtin_amdgcn_global_load_lds(
        (const __attribute__((address_space(1))) unsigned int*)g,
        (__attribute__((address_space(3))) unsigned int*)l, 16, 0, 0);
}

// ---------------- fused pre-pass: K f32->bf16 linear, V f32->bf16 transposed+permuted ----
__global__ void cvt_kv_kernel(const float* __restrict__ K, const float* __restrict__ V,
                              short* __restrict__ Kb, short* __restrict__ Vt) {
    const int h   = blockIdx.y;
    const int tid = threadIdx.x;
    {
        const int base = ((h * SEQ + blockIdx.x * 16) * DH) >> 2;   // float4 idx
        #pragma unroll
        for (int j = 0; j < 2; ++j) {
            const int i = base + tid + j * 256;
            const float4 v = ((const float4*)K)[i];
            short4 o;
            o.x = f2bf(v.x); o.y = f2bf(v.y); o.z = f2bf(v.z); o.w = f2bf(v.w);
            ((short4*)Kb)[i] = o;
        }
    }
    {
        const int s8 = blockIdx.x * 2 + (tid >> 7);
        const int d  = tid & 127;
        const int s0 = s8 * 8;                       // 8 consecutive keys
        const float* src = V + ((size_t)h * SEQ + s0) * DH + d;
        short8 w;
        #pragma unroll
        for (int j = 0; j < 8; ++j) w[j] = f2bf(src[j * DH]);
        // lambda-permuted positions within the 64-key tile
        const int tb   = s0 & ~63;
        const int j0   = s0 & 63;
        const int ks2  = j0 >> 5;
        const int jm   = j0 & 15;
        const int hi   = (j0 >> 4) & 1;
        const int pos0 = ks2 * 32 + (jm >> 2) * 8 + hi * 4;
        short* dst = Vt + ((size_t)h * DH + d) * SEQ + tb;
        short4 lo4, hi4;
        lo4.x = w[0]; lo4.y = w[1]; lo4.z = w[2]; lo4.w = w[3];
        hi4.x = w[4]; hi4.y = w[5]; hi4.z = w[6]; hi4.w = w[7];
        *(short4*)(dst + pos0)     = lo4;
        *(short4*)(dst + pos0 + 8) = hi4;
    }
}

// ---------------- MFMA flash attention: swapped-QK, 4 waves x 32 q-rows ----------------
__global__ __launch_bounds__(256, 3)
void attn_mfma(const float* __restrict__ Q, const short* __restrict__ Kb,
               const short* __restrict__ Vtg, const float* __restrict__ ref_mask,
               const float* __restrict__ routing, float* __restrict__ out)
{
    __shared__ short Ks[64 * 128];     // [key][chunk^(key&7)] bf16
    __shared__ short Vs[128 * 64];     // [d][kc^(d&7)] bf16 (lambda-permuted keys)

    const int bid  = blockIdx.x;
    const int h    = bid % NH;          // same head -> same (bid%8) -> same XCD
    const int bx   = bid / NH;          // 0..25, heavy blocks dispatch first
    const int tid  = threadIdx.x;
    const int wave = tid >> 6, lane = tid & 63;
    const int g    = lane >> 4, l4 = lane & 15;

    int qbase, ks0 = 0, ntiles;
    bool masked = false, router = false;
    if (bx < 21)       { qbase = bx * 128; ntiles = 49; masked = true; }
    else if (bx == 21) { qbase = TRIR; ntiles = 33; router = true; }
    else {
        const int b2 = bx - 22;
        qbase = TRI + b2 * 128;
        ks0 = TRI + (b2 >> 1) * 256; ntiles = 4;
    }

    const int rbase = qbase + wave * 32;             // this wave's 32 q rows (2 x 16)
    const bool valid = !(masked && rbase >= TRI) && !(router && wave >= 1);

    // ---- staging address precompute (pre-swizzled global source, linear LDS dest) ----
    const short* KbH = Kb  + (size_t)h * SEQ * DH;
    const short* VtH = Vtg + (size_t)h * DH * SEQ;
    int koff[4], vD[4], vKC[4], voff[4];
    short *ksd[4], *vsd[4];
    #pragma unroll
    for (int j = 0; j < 4; ++j) {
        const int ci = tid + j * 256;
        const int kk = ci >> 4, kc = ci & 15;
        koff[j] = kk * 128 + ((kc ^ (kk & 7)) << 3);
        const int vd = ci >> 3, vk = ci & 7;
        vD[j] = vd; vKC[j] = vk;
        voff[j] = vd * SEQ + ((vk ^ (vd & 7)) << 3);
        ksd[j] = Ks + (size_t)(j * 256 + wave * 64) * 8;
        vsd[j] = Vs + (size_t)(j * 256 + wave * 64) * 8;
    }

    // ---- Q fragments (pre-scaled to log2 domain): qA[qt][ks], row = qt*16+l4 ----
    short8 qA[2][4];
    if (valid) {
        #pragma unroll
        for (int qt = 0; qt < 2; ++qt) {
            const int q = rbase + qt * 16 + l4;
            const float* qp = Q + ((size_t)h * SEQ + q) * DH;
            #pragma unroll
            for (int ks = 0; ks < 4; ++ks) {
                const float4 a = *(const float4*)(qp + ks * 32 + g * 8);
                const float4 b = *(const float4*)(qp + ks * 32 + g * 8 + 4);
                short8 f;
                f[0] = f2bf(a.x * QSC); f[1] = f2bf(a.y * QSC);
                f[2] = f2bf(a.z * QSC); f[3] = f2bf(a.w * QSC);
                f[4] = f2bf(b.x * QSC); f[5] = f2bf(b.y * QSC);
                f[6] = f2bf(b.z * QSC); f[7] = f2bf(b.w * QSC);
                qA[qt][ks] = f;
            }
        }
    }

    f32x4 acc[2][8] = {};
    float m_run[2] = {-3.0e38f, -3.0e38f}, l_run[2] = {0.f, 0.f};
    const int bsrc = (lane >> 4) << 2;               // shuffle source base g*4

    for (int t = 0; t < ntiles; ++t) {
        const int kt = masked ? t * 64
                     : (router ? (t < 32 ? TRE + t * 64 : TRIR) : ks0 + t * 64);
        const bool tail = router && (t == 32);       // only 32 of 64 keys valid
        __syncthreads();                             // A: previous tile consumed
        const short* kb = KbH + (size_t)kt * DH;
        const short* vb = VtH + kt;
        #pragma unroll
        for (int j = 0; j < 4; ++j) {
            const int ko = tail ? (koff[j] & 4095) : koff[j];
            gload16(kb + ko, ksd[j]);
        }
        #pragma unroll
        for (int j = 0; j < 4; ++j) {
            const int vo = tail ? (vD[j] * SEQ + (((vKC[j] ^ (vD[j] & 7)) & 3) << 3))
                                : voff[j];
            gload16(vb + vo, vsd[j]);
        }
        __syncthreads();                             // B: drains vmcnt + barrier

        if (!valid) continue;

        // ---- QK^T swapped: s[qt][nt][r] = S[key = nt*16+g*4+r][q = rbase+qt*16+l4] ----
        // each kB fragment loaded ONCE, used for both qt (halves LDS read traffic)
        f32x4 s[2][4] = {};
        __builtin_amdgcn_s_setprio(1);
        #pragma unroll
        for (int nt = 0; nt < 4; ++nt) {
            const int key = nt * 16 + l4;
            #pragma unroll
            for (int ks = 0; ks < 4; ++ks) {
                const short8 kB = *(const short8*)(Ks + key * 128 + (((ks * 4 + g) ^ (key & 7)) << 3));
                s[0][nt] = __builtin_amdgcn_mfma_f32_16x16x32_bf16(kB, qA[0][ks], s[0][nt], 0, 0, 0);
                s[1][nt] = __builtin_amdgcn_mfma_f32_16x16x32_bf16(kB, qA[1][ks], s[1][nt], 0, 0, 0);
            }
        }
        __builtin_amdgcn_s_setprio(0);

        // ---- masks (f32 exact, log2 domain), swapped orientation, per qt ----
        if (masked) {
            if (kt >= TRI) {                         // ref-key tiles
                const int cr = (kt - TRI) >> 8;
                const int j0 = kt - TRI + g * 4;
                #pragma unroll
                for (int qt = 0; qt < 2; ++qt) {
                    const int q  = rbase + qt * 16 + l4;
                    const bool hr = rbase >= TRE;    // block-row uniform (rbase>=TRE covers both qt)
                    float radd = 0.f;
                    if (hr) radd = routing[cr * IMG + (q - TRE)] * C100 - C100;
                    #pragma unroll
                    for (int nt = 0; nt < 4; ++nt)
                        #pragma unroll
                        for (int r = 0; r < 4; ++r) {
                            const float rmv = ref_mask[(size_t)(j0 + nt * 16 + r) * TRI + q];
                            s[qt][nt][r] += rmv * C100 - CREF + radd;
                        }
                }
            } else if (kt == TXT) {                  // redux-key tile
                if (rbase >= TRE) {
                    #pragma unroll
                    for (int qt = 0; qt < 2; ++qt) {
                        const int q = rbase + qt * 16 + l4;
                        const float a0 = routing[q - TRE] * C100 - C100;
                        const float a1 = routing[IMG + q - TRE] * C100 - C100;
                        #pragma unroll
                        for (int nt = 0; nt < 4; ++nt)
                            #pragma unroll
                            for (int r = 0; r < 4; ++r)
                                s[qt][nt][r] += (nt >> 1) ? a1 : a0;
                    }
                }
            }
        }
        if (tail) {                                  // router tail: keys >= SEQ invalid
            #pragma unroll
            for (int qt = 0; qt < 2; ++qt)
                #pragma unroll
                for (int r = 0; r < 4; ++r) { s[qt][2][r] = -3.0e38f; s[qt][3][r] = -3.0e38f; }
        }

        // ---- softmax per qt: lane-local + 2 cross-group shuffles ----
        float mx[2];
        #pragma unroll
        for (int qt = 0; qt < 2; ++qt) {
            float m0 = fmaxf(fmaxf(s[qt][0][0], s[qt][0][1]), fmaxf(s[qt][0][2], s[qt][0][3]));
            m0 = fmaxf(m0, fmaxf(fmaxf(s[qt][1][0], s[qt][1][1]), fmaxf(s[qt][1][2], s[qt][1][3])));
            m0 = fmaxf(m0, fmaxf(fmaxf(s[qt][2][0], s[qt][2][1]), fmaxf(s[qt][2][2], s[qt][2][3])));
            m0 = fmaxf(m0, fmaxf(fmaxf(s[qt][3][0], s[qt][3][1]), fmaxf(s[qt][3][2], s[qt][3][3])));
            m0 = fmaxf(m0, __shfl_xor(m0, 16));
            m0 = fmaxf(m0, __shfl_xor(m0, 32));
            mx[qt] = m0;
        }

        const float gmax = fmaxf(mx[0] - m_run[0], mx[1] - m_run[1]);
        if (__any(gmax > THR2)) {                    // defer-max rescale (rare)
            #pragma unroll
            for (int qt = 0; qt < 2; ++qt) {
                const float mn    = fmaxf(m_run[qt], mx[qt]);
                const float corrq = exp2f(m_run[qt] - mn);
                m_run[qt] = mn;
                l_run[qt] *= corrq;
                f32x4 corr;
                #pragma unroll
                for (int r = 0; r < 4; ++r) corr[r] = __shfl(corrq, bsrc + r);
                #pragma unroll
                for (int nt = 0; nt < 8; ++nt)
                    #pragma unroll
                    for (int r = 0; r < 4; ++r) acc[qt][nt][r] *= corr[r];
            }
        }

        short8 pA[2][2];                             // [qt][ks2], lambda slot order
        #pragma unroll
        for (int qt = 0; qt < 2; ++qt) {
            float rsum = 0.f;
            #pragma unroll
            for (int nt = 0; nt < 4; ++nt)
                #pragma unroll
                for (int r = 0; r < 4; ++r) {
                    s[qt][nt][r] = exp2f(s[qt][nt][r] - m_run[qt]);
                    rsum += s[qt][nt][r];
                }
            rsum += __shfl_xor(rsum, 16);
            rsum += __shfl_xor(rsum, 32);
            l_run[qt] += rsum;
            #pragma unroll
            for (int j = 0; j < 4; ++j) {
                pA[qt][0][j]     = f2bf(s[qt][0][j]);
                pA[qt][0][4 + j] = f2bf(s[qt][1][j]);
                pA[qt][1][j]     = f2bf(s[qt][2][j]);
                pA[qt][1][4 + j] = f2bf(s[qt][3][j]);
            }
        }

        // ---- PV: vB loaded ONCE per (ks2,nt), used for both qt ----
        __builtin_amdgcn_s_setprio(1);
        #pragma unroll
        for (int ks2 = 0; ks2 < 2; ++ks2) {
            const int kc = ks2 * 4 + g;              // permuted chunk holding lambda(g,0..7)
            #pragma unroll
            for (int nt = 0; nt < 8; ++nt) {
                const int d = nt * 16 + l4;
                const short8 vB = *(const short8*)(Vs + d * 64 + ((kc ^ (d & 7)) << 3));
                acc[0][nt] = __builtin_amdgcn_mfma_f32_16x16x32_bf16(pA[0][ks2], vB, acc[0][nt], 0, 0, 0);
                acc[1][nt] = __builtin_amdgcn_mfma_f32_16x16x32_bf16(pA[1][ks2], vB, acc[1][nt], 0, 0, 0);
            }
        }
        __builtin_amdgcn_s_setprio(0);
    }

    if (valid) {
        #pragma unroll
        for (int qt = 0; qt < 2; ++qt) {
            f32x4 linv;
            #pragma unroll
            for (int r = 0; r < 4; ++r) linv[r] = 1.0f / __shfl(l_run[qt], bsrc + r);
            #pragma unroll
            for (int nt = 0; nt < 8; ++nt)
                #pragma unroll
                for (int r = 0; r < 4; ++r) {
                    const int q = rbase + qt * 16 + g * 4 + r;
                    out[((size_t)h * SEQ + q) * DH + nt * 16 + l4] = acc[qt][nt][r] * linv[r];
                }
        }
    }
}

// ---------------- scalar kernel (full fallback only; uses raw f32 K/V) ----------------
#define KT  32
#define LDK (DH + 4)
__global__ __launch_bounds__(256, 2)
void anystory_attn_scalar(const float* __restrict__ Q, const float* __restrict__ K,
                          const float* __restrict__ V, const float* __restrict__ ref_mask,
                          const float* __restrict__ routing, float* __restrict__ out, int row0)
{
    __shared__ float KsS[KT][LDK];
    __shared__ float VsS[KT][LDK];

    const int h    = blockIdx.y;
    const int r0   = row0 + blockIdx.x * 4;
    const int tid  = threadIdx.x;
    const int wave = tid >> 6;
    const int lane = tid & 63;
    const int key_l = lane & 31;
    const int half  = lane >> 5;
    const int row  = r0 + wave;

    int rs0, re0, rs1 = 0, re1 = 0;
    bool masked = false;
    if (r0 < TRI) { rs0 = 0; re0 = TRIR; masked = true; }
    else if (r0 < TRIR) {
        int c = (r0 - TRI) / (REFN / NC);
        rs0 = TRI + c * (REFN / NC); re0 = rs0 + (REFN / NC);
    } else { rs0 = TRE; re0 = TRI; rs1 = TRIR; re1 = SEQ; }

    float4 qreg[16];
    const float4* qptr = (const float4*)(Q + ((size_t)h * SEQ + row) * DH + half * 64);
    #pragma unroll
    for (int i = 0; i < 16; ++i) qreg[i] = qptr[i];

    float m = -1e30f, l = 0.f, acc0 = 0.f, acc1 = 0.f;

    for (int range = 0; range < 2; ++range) {
        const int ks = (range == 0) ? rs0 : rs1;
        const int ke = (range == 0) ? re0 : re1;
        for (int kt = ks; kt < ke; kt += KT) {
            __syncthreads();
            #pragma unroll
            for (int i = 0; i < 4; ++i) {
                int idx = tid + i * 256;
                int rr = idx >> 5, cc = (idx & 31) * 4;
                const float4 kv = ((const float4*)(K + ((size_t)h * SEQ + kt + rr) * DH))[idx & 31];
                const float4 vv = ((const float4*)(V + ((size_t)h * SEQ + kt + rr) * DH))[idx & 31];
                *(float4*)&KsS[rr][cc] = kv;
                *(float4*)&VsS[rr][cc] = vv;
            }
            __syncthreads();

            const int kglob = kt + key_l;
            float dot = 0.f;
            #pragma unroll
            for (int i = 0; i < 16; ++i) {
                float4 k4 = *(const float4*)&KsS[key_l][half * 64 + i * 4];
                dot += qreg[i].x * k4.x + qreg[i].y * k4.y + qreg[i].z * k4.z + qreg[i].w * k4.w;
            }
            dot += __shfl_xor(dot, 32);
            float logit = dot * SCALE;

            if (masked) {
                if (kglob >= TRI) {
                    logit += 1.5f + (ref_mask[(size_t)(kglob - TRI) * TRI + row] - 1.f) * 100.f;
                    if (row >= TRE)
                        logit += (routing[((kglob - TRI) >> 8) * IMG + (row - TRE)] - 1.f) * 100.f;
                } else if (kglob >= TXT && kglob < TRE && row >= TRE) {
                    logit += (routing[((kglob - TXT) >> 5) * IMG + (row - TRE)] - 1.f) * 100.f;
                }
            }

            float tm = logit;
            tm = fmaxf(tm, __shfl_xor(tm, 1));
            tm = fmaxf(tm, __shfl_xor(tm, 2));
            tm = fmaxf(tm, __shfl_xor(tm, 4));
            tm = fmaxf(tm, __shfl_xor(tm, 8));
            tm = fmaxf(tm, __shfl_xor(tm, 16));
            const float nm   = fmaxf(m, tm);
            const float corr = __expf(m - nm);
            const float p    = __expf(logit - nm);
            float ps = p;
            ps += __shfl_xor(ps, 1);
            ps += __shfl_xor(ps, 2);
            ps += __shfl_xor(ps, 4);
            ps += __shfl_xor(ps, 8);
            ps += __shfl_xor(ps, 16);
            l = l * corr + ps;
            acc0 *= corr; acc1 *= corr;
            m = nm;

            #pragma unroll
            for (int k = 0; k < KT; ++k) {
                const float pk = __shfl(p, k);
                acc0 += pk * VsS[k][lane];
                acc1 += pk * VsS[k][lane + 64];
            }
        }
    }

    const float inv = 1.f / l;
    float* op = out + ((size_t)h * SEQ + row) * DH;
    op[lane]      = acc0 * inv;
    op[lane + 64] = acc1 * inv;
}

extern "C" void kernel_launch(void* const* d_in, const int* in_sizes, int n_in,
                              void* d_out, int out_size, void* d_ws, size_t ws_size,
                              hipStream_t stream) {
    const float* Q        = (const float*)d_in[0];
    const float* K        = (const float*)d_in[1];
    const float* V        = (const float*)d_in[2];
    const float* ref_mask = (const float*)d_in[3];
    const float* routing  = (const float*)d_in[4];
    float* out = (float*)d_out;

    const size_t elems = (size_t)NH * SEQ * DH;
    const size_t need  = 2 * elems * sizeof(short);

    if (ws_size < need) {
        dim3 grid(SEQ / 4, NH);
        anystory_attn_scalar<<<grid, 256, 0, stream>>>(Q, K, V, ref_mask, routing, out, 0);
        return;
    }

    short* Kb  = (short*)d_ws;
    short* Vtg = Kb + elems;

    cvt_kv_kernel<<<dim3(SEQ / 16, NH), 256, 0, stream>>>(K, V, Kb, Vtg);

    // 26 block-cols per head (21 heavy, 1 router, 4 ref), head-major for XCD L2 locality
    attn_mfma<<<dim3(NH * 26), 256, 0, stream>>>(Q, Kb, Vtg, ref_mask, routing, out);
}

// Round 12
// 237.298 us; speedup vs baseline: 1.3398x; 1.3398x over previous
//
#include <hip/hip_runtime.h>
#include <hip/hip_bf16.h>

#define TXT   512
#define REDUX 64
#define IMG   2048
#define REFN  512
#define NC    2
#define SEQ   3168
#define DH    128
#define NH    24
#define TRE   576
#define TRI   2624
#define TRIR  3136
#define SCALE 0.08838834764831845f
#define L2E   1.4426950408889634f
#define QSC   (SCALE * L2E)          // scale folded with log2(e)
#define C100  (100.0f * L2E)         // 144.2695
#define CREF  (98.5f * L2E)          // 142.1055
#define THR2  (4.0f * L2E)           // defer-max threshold in log2 units

using f32x4  = __attribute__((ext_vector_type(4))) float;
using short8 = __attribute__((ext_vector_type(8))) short;

__device__ inline short f2bf(float x) {
    union { __hip_bfloat16 b; short s; } u;
    u.b = __float2bfloat16(x);
    return u.s;
}

__device__ inline void gload16(const short* g, short* l) {
    __builtin_amdgcn_global_load_lds(
        (const __attribute__((address_space(1))) unsigned int*)g,
        (__attribute__((address_space(3))) unsigned int*)l, 16, 0, 0);
}

// ---------------- fused pre-pass: K f32->bf16 linear, V f32->bf16 transposed+permuted ----
__global__ void cvt_kv_kernel(const float* __restrict__ K, const float* __restrict__ V,
                              short* __restrict__ Kb, short* __restrict__ Vt) {
    const int h   = blockIdx.y;
    const int tid = threadIdx.x;
    {
        const int base = ((h * SEQ + blockIdx.x * 16) * DH) >> 2;   // float4 idx
        #pragma unroll
        for (int j = 0; j < 2; ++j) {
            const int i = base + tid + j * 256;
            const float4 v = ((const float4*)K)[i];
            short4 o;
            o.x = f2bf(v.x); o.y = f2bf(v.y); o.z = f2bf(v.z); o.w = f2bf(v.w);
            ((short4*)Kb)[i] = o;
        }
    }
    {
        const int s8 = blockIdx.x * 2 + (tid >> 7);
        const int d  = tid & 127;
        const int s0 = s8 * 8;                       // 8 consecutive keys
        const float* src = V + ((size_t)h * SEQ + s0) * DH + d;
        short8 w;
        #pragma unroll
        for (int j = 0; j < 8; ++j) w[j] = f2bf(src[j * DH]);
        // lambda-permuted positions within the 64-key tile
        const int tb   = s0 & ~63;
        const int j0   = s0 & 63;
        const int ks2  = j0 >> 5;
        const int jm   = j0 & 15;
        const int hi   = (j0 >> 4) & 1;
        const int pos0 = ks2 * 32 + (jm >> 2) * 8 + hi * 4;
        short* dst = Vt + ((size_t)h * DH + d) * SEQ + tb;
        short4 lo4, hi4;
        lo4.x = w[0]; lo4.y = w[1]; lo4.z = w[2]; lo4.w = w[3];
        hi4.x = w[4]; hi4.y = w[5]; hi4.z = w[6]; hi4.w = w[7];
        *(short4*)(dst + pos0)     = lo4;
        *(short4*)(dst + pos0 + 8) = hi4;
    }
}

// ---------------- MFMA flash attention: swapped-QK, 4 waves x 32 q-rows ----------------
// launch_bounds(256,2): VGPR cap 128 -> no spill (R11's (256,3) cap=85 spilled acc/qA,
// +300MB scratch traffic through L2). VGPR<=128 keeps the 4-waves/SIMD occupancy band.
__global__ __launch_bounds__(256, 2)
void attn_mfma(const float* __restrict__ Q, const short* __restrict__ Kb,
               const short* __restrict__ Vtg, const float* __restrict__ ref_mask,
               const float* __restrict__ routing, float* __restrict__ out)
{
    __shared__ short Ks[64 * 128];     // [key][chunk^(key&7)] bf16
    __shared__ short Vs[128 * 64];     // [d][kc^(d&7)] bf16 (lambda-permuted keys)

    const int bid  = blockIdx.x;
    const int h    = bid % NH;          // same head -> same (bid%8) -> same XCD
    const int bx   = bid / NH;          // 0..25, heavy blocks dispatch first
    const int tid  = threadIdx.x;
    const int wave = tid >> 6, lane = tid & 63;
    const int g    = lane >> 4, l4 = lane & 15;

    int qbase, ks0 = 0, ntiles;
    bool masked = false, router = false;
    if (bx < 21)       { qbase = bx * 128; ntiles = 49; masked = true; }
    else if (bx == 21) { qbase = TRIR; ntiles = 33; router = true; }
    else {
        const int b2 = bx - 22;
        qbase = TRI + b2 * 128;
        ks0 = TRI + (b2 >> 1) * 256; ntiles = 4;
    }

    const int rbase = qbase + wave * 32;             // this wave's 32 q rows (2 x 16)
    const bool valid = !(masked && rbase >= TRI) && !(router && wave >= 1);

    // ---- staging address precompute (pre-swizzled global source, linear LDS dest) ----
    const short* KbH = Kb  + (size_t)h * SEQ * DH;
    const short* VtH = Vtg + (size_t)h * DH * SEQ;
    int koff[4], vD[4], vKC[4], voff[4];
    short *ksd[4], *vsd[4];
    #pragma unroll
    for (int j = 0; j < 4; ++j) {
        const int ci = tid + j * 256;
        const int kk = ci >> 4, kc = ci & 15;
        koff[j] = kk * 128 + ((kc ^ (kk & 7)) << 3);
        const int vd = ci >> 3, vk = ci & 7;
        vD[j] = vd; vKC[j] = vk;
        voff[j] = vd * SEQ + ((vk ^ (vd & 7)) << 3);
        ksd[j] = Ks + (size_t)(j * 256 + wave * 64) * 8;
        vsd[j] = Vs + (size_t)(j * 256 + wave * 64) * 8;
    }

    // ---- Q fragments (pre-scaled to log2 domain): qA[qt][ks], row = qt*16+l4 ----
    short8 qA[2][4];
    if (valid) {
        #pragma unroll
        for (int qt = 0; qt < 2; ++qt) {
            const int q = rbase + qt * 16 + l4;
            const float* qp = Q + ((size_t)h * SEQ + q) * DH;
            #pragma unroll
            for (int ks = 0; ks < 4; ++ks) {
                const float4 a = *(const float4*)(qp + ks * 32 + g * 8);
                const float4 b = *(const float4*)(qp + ks * 32 + g * 8 + 4);
                short8 f;
                f[0] = f2bf(a.x * QSC); f[1] = f2bf(a.y * QSC);
                f[2] = f2bf(a.z * QSC); f[3] = f2bf(a.w * QSC);
                f[4] = f2bf(b.x * QSC); f[5] = f2bf(b.y * QSC);
                f[6] = f2bf(b.z * QSC); f[7] = f2bf(b.w * QSC);
                qA[qt][ks] = f;
            }
        }
    }

    f32x4 acc[2][8] = {};
    float m_run[2] = {-3.0e38f, -3.0e38f}, l_run[2] = {0.f, 0.f};
    const int bsrc = (lane >> 4) << 2;               // shuffle source base g*4

    for (int t = 0; t < ntiles; ++t) {
        const int kt = masked ? t * 64
                     : (router ? (t < 32 ? TRE + t * 64 : TRIR) : ks0 + t * 64);
        const bool tail = router && (t == 32);       // only 32 of 64 keys valid
        __syncthreads();                             // A: previous tile consumed
        const short* kb = KbH + (size_t)kt * DH;
        const short* vb = VtH + kt;
        #pragma unroll
        for (int j = 0; j < 4; ++j) {
            const int ko = tail ? (koff[j] & 4095) : koff[j];
            gload16(kb + ko, ksd[j]);
        }
        #pragma unroll
        for (int j = 0; j < 4; ++j) {
            const int vo = tail ? (vD[j] * SEQ + (((vKC[j] ^ (vD[j] & 7)) & 3) << 3))
                                : voff[j];
            gload16(vb + vo, vsd[j]);
        }
        __syncthreads();                             // B: drains vmcnt + barrier

        if (!valid) continue;

        // ---- QK^T swapped: s[qt][nt][r] = S[key = nt*16+g*4+r][q = rbase+qt*16+l4] ----
        // each kB fragment loaded ONCE, used for both qt (halves LDS read traffic)
        f32x4 s[2][4] = {};
        __builtin_amdgcn_s_setprio(1);
        #pragma unroll
        for (int nt = 0; nt < 4; ++nt) {
            const int key = nt * 16 + l4;
            #pragma unroll
            for (int ks = 0; ks < 4; ++ks) {
                const short8 kB = *(const short8*)(Ks + key * 128 + (((ks * 4 + g) ^ (key & 7)) << 3));
                s[0][nt] = __builtin_amdgcn_mfma_f32_16x16x32_bf16(kB, qA[0][ks], s[0][nt], 0, 0, 0);
                s[1][nt] = __builtin_amdgcn_mfma_f32_16x16x32_bf16(kB, qA[1][ks], s[1][nt], 0, 0, 0);
            }
        }
        __builtin_amdgcn_s_setprio(0);

        // ---- masks (f32 exact, log2 domain), swapped orientation, per qt ----
        if (masked) {
            if (kt >= TRI) {                         // ref-key tiles
                const int cr = (kt - TRI) >> 8;
                const int j0 = kt - TRI + g * 4;
                #pragma unroll
                for (int qt = 0; qt < 2; ++qt) {
                    const int q  = rbase + qt * 16 + l4;
                    const bool hr = rbase >= TRE;
                    float radd = 0.f;
                    if (hr) radd = routing[cr * IMG + (q - TRE)] * C100 - C100;
                    #pragma unroll
                    for (int nt = 0; nt < 4; ++nt)
                        #pragma unroll
                        for (int r = 0; r < 4; ++r) {
                            const float rmv = ref_mask[(size_t)(j0 + nt * 16 + r) * TRI + q];
                            s[qt][nt][r] += rmv * C100 - CREF + radd;
                        }
                }
            } else if (kt == TXT) {                  // redux-key tile
                if (rbase >= TRE) {
                    #pragma unroll
                    for (int qt = 0; qt < 2; ++qt) {
                        const int q = rbase + qt * 16 + l4;
                        const float a0 = routing[q - TRE] * C100 - C100;
                        const float a1 = routing[IMG + q - TRE] * C100 - C100;
                        #pragma unroll
                        for (int nt = 0; nt < 4; ++nt)
                            #pragma unroll
                            for (int r = 0; r < 4; ++r)
                                s[qt][nt][r] += (nt >> 1) ? a1 : a0;
                    }
                }
            }
        }
        if (tail) {                                  // router tail: keys >= SEQ invalid
            #pragma unroll
            for (int qt = 0; qt < 2; ++qt)
                #pragma unroll
                for (int r = 0; r < 4; ++r) { s[qt][2][r] = -3.0e38f; s[qt][3][r] = -3.0e38f; }
        }

        // ---- softmax per qt: lane-local + 2 cross-group shuffles ----
        float mx[2];
        #pragma unroll
        for (int qt = 0; qt < 2; ++qt) {
            float m0 = fmaxf(fmaxf(s[qt][0][0], s[qt][0][1]), fmaxf(s[qt][0][2], s[qt][0][3]));
            m0 = fmaxf(m0, fmaxf(fmaxf(s[qt][1][0], s[qt][1][1]), fmaxf(s[qt][1][2], s[qt][1][3])));
            m0 = fmaxf(m0, fmaxf(fmaxf(s[qt][2][0], s[qt][2][1]), fmaxf(s[qt][2][2], s[qt][2][3])));
            m0 = fmaxf(m0, fmaxf(fmaxf(s[qt][3][0], s[qt][3][1]), fmaxf(s[qt][3][2], s[qt][3][3])));
            m0 = fmaxf(m0, __shfl_xor(m0, 16));
            m0 = fmaxf(m0, __shfl_xor(m0, 32));
            mx[qt] = m0;
        }

        const float gmax = fmaxf(mx[0] - m_run[0], mx[1] - m_run[1]);
        if (__any(gmax > THR2)) {                    // defer-max rescale (rare)
            #pragma unroll
            for (int qt = 0; qt < 2; ++qt) {
                const float mn    = fmaxf(m_run[qt], mx[qt]);
                const float corrq = exp2f(m_run[qt] - mn);
                m_run[qt] = mn;
                l_run[qt] *= corrq;
                f32x4 corr;
                #pragma unroll
                for (int r = 0; r < 4; ++r) corr[r] = __shfl(corrq, bsrc + r);
                #pragma unroll
                for (int nt = 0; nt < 8; ++nt)
                    #pragma unroll
                    for (int r = 0; r < 4; ++r) acc[qt][nt][r] *= corr[r];
            }
        }

        short8 pA[2][2];                             // [qt][ks2], lambda slot order
        #pragma unroll
        for (int qt = 0; qt < 2; ++qt) {
            float rsum = 0.f;
            #pragma unroll
            for (int nt = 0; nt < 4; ++nt)
                #pragma unroll
                for (int r = 0; r < 4; ++r) {
                    s[qt][nt][r] = exp2f(s[qt][nt][r] - m_run[qt]);
                    rsum += s[qt][nt][r];
                }
            rsum += __shfl_xor(rsum, 16);
            rsum += __shfl_xor(rsum, 32);
            l_run[qt] += rsum;
            #pragma unroll
            for (int j = 0; j < 4; ++j) {
                pA[qt][0][j]     = f2bf(s[qt][0][j]);
                pA[qt][0][4 + j] = f2bf(s[qt][1][j]);
                pA[qt][1][j]     = f2bf(s[qt][2][j]);
                pA[qt][1][4 + j] = f2bf(s[qt][3][j]);
            }
        }

        // ---- PV: vB loaded ONCE per (ks2,nt), used for both qt ----
        __builtin_amdgcn_s_setprio(1);
        #pragma unroll
        for (int ks2 = 0; ks2 < 2; ++ks2) {
            const int kc = ks2 * 4 + g;              // permuted chunk holding lambda(g,0..7)
            #pragma unroll
            for (int nt = 0; nt < 8; ++nt) {
                const int d = nt * 16 + l4;
                const short8 vB = *(const short8*)(Vs + d * 64 + ((kc ^ (d & 7)) << 3));
                acc[0][nt] = __builtin_amdgcn_mfma_f32_16x16x32_bf16(pA[0][ks2], vB, acc[0][nt], 0, 0, 0);
                acc[1][nt] = __builtin_amdgcn_mfma_f32_16x16x32_bf16(pA[1][ks2], vB, acc[1][nt], 0, 0, 0);
            }
        }
        __builtin_amdgcn_s_setprio(0);
    }

    if (valid) {
        #pragma unroll
        for (int qt = 0; qt < 2; ++qt) {
            f32x4 linv;
            #pragma unroll
            for (int r = 0; r < 4; ++r) linv[r] = 1.0f / __shfl(l_run[qt], bsrc + r);
            #pragma unroll
            for (int nt = 0; nt < 8; ++nt)
                #pragma unroll
                for (int r = 0; r < 4; ++r) {
                    const int q = rbase + qt * 16 + g * 4 + r;
                    out[((size_t)h * SEQ + q) * DH + nt * 16 + l4] = acc[qt][nt][r] * linv[r];
                }
        }
    }
}

// ---------------- scalar kernel (full fallback only; uses raw f32 K/V) ----------------
#define KT  32
#define LDK (DH + 4)
__global__ __launch_bounds__(256, 2)
void anystory_attn_scalar(const float* __restrict__ Q, const float* __restrict__ K,
                          const float* __restrict__ V, const float* __restrict__ ref_mask,
                          const float* __restrict__ routing, float* __restrict__ out, int row0)
{
    __shared__ float KsS[KT][LDK];
    __shared__ float VsS[KT][LDK];

    const int h    = blockIdx.y;
    const int r0   = row0 + blockIdx.x * 4;
    const int tid  = threadIdx.x;
    const int wave = tid >> 6;
    const int lane = tid & 63;
    const int key_l = lane & 31;
    const int half  = lane >> 5;
    const int row  = r0 + wave;

    int rs0, re0, rs1 = 0, re1 = 0;
    bool masked = false;
    if (r0 < TRI) { rs0 = 0; re0 = TRIR; masked = true; }
    else if (r0 < TRIR) {
        int c = (r0 - TRI) / (REFN / NC);
        rs0 = TRI + c * (REFN / NC); re0 = rs0 + (REFN / NC);
    } else { rs0 = TRE; re0 = TRI; rs1 = TRIR; re1 = SEQ; }

    float4 qreg[16];
    const float4* qptr = (const float4*)(Q + ((size_t)h * SEQ + row) * DH + half * 64);
    #pragma unroll
    for (int i = 0; i < 16; ++i) qreg[i] = qptr[i];

    float m = -1e30f, l = 0.f, acc0 = 0.f, acc1 = 0.f;

    for (int range = 0; range < 2; ++range) {
        const int ks = (range == 0) ? rs0 : rs1;
        const int ke = (range == 0) ? re0 : re1;
        for (int kt = ks; kt < ke; kt += KT) {
            __syncthreads();
            #pragma unroll
            for (int i = 0; i < 4; ++i) {
                int idx = tid + i * 256;
                int rr = idx >> 5, cc = (idx & 31) * 4;
                const float4 kv = ((const float4*)(K + ((size_t)h * SEQ + kt + rr) * DH))[idx & 31];
                const float4 vv = ((const float4*)(V + ((size_t)h * SEQ + kt + rr) * DH))[idx & 31];
                *(float4*)&KsS[rr][cc] = kv;
                *(float4*)&VsS[rr][cc] = vv;
            }
            __syncthreads();

            const int kglob = kt + key_l;
            float dot = 0.f;
            #pragma unroll
            for (int i = 0; i < 16; ++i) {
                float4 k4 = *(const float4*)&KsS[key_l][half * 64 + i * 4];
                dot += qreg[i].x * k4.x + qreg[i].y * k4.y + qreg[i].z * k4.z + qreg[i].w * k4.w;
            }
            dot += __shfl_xor(dot, 32);
            float logit = dot * SCALE;

            if (masked) {
                if (kglob >= TRI) {
                    logit += 1.5f + (ref_mask[(size_t)(kglob - TRI) * TRI + row] - 1.f) * 100.f;
                    if (row >= TRE)
                        logit += (routing[((kglob - TRI) >> 8) * IMG + (row - TRE)] - 1.f) * 100.f;
                } else if (kglob >= TXT && kglob < TRE && row >= TRE) {
                    logit += (routing[((kglob - TXT) >> 5) * IMG + (row - TRE)] - 1.f) * 100.f;
                }
            }

            float tm = logit;
            tm = fmaxf(tm, __shfl_xor(tm, 1));
            tm = fmaxf(tm, __shfl_xor(tm, 2));
            tm = fmaxf(tm, __shfl_xor(tm, 4));
            tm = fmaxf(tm, __shfl_xor(tm, 8));
            tm = fmaxf(tm, __shfl_xor(tm, 16));
            const float nm   = fmaxf(m, tm);
            const float corr = __expf(m - nm);
            const float p    = __expf(logit - nm);
            float ps = p;
            ps += __shfl_xor(ps, 1);
            ps += __shfl_xor(ps, 2);
            ps += __shfl_xor(ps, 4);
            ps += __shfl_xor(ps, 8);
            ps += __shfl_xor(ps, 16);
            l = l * corr + ps;
            acc0 *= corr; acc1 *= corr;
            m = nm;

            #pragma unroll
            for (int k = 0; k < KT; ++k) {
                const float pk = __shfl(p, k);
                acc0 += pk * VsS[k][lane];
                acc1 += pk * VsS[k][lane + 64];
            }
        }
    }

    const float inv = 1.f / l;
    float* op = out + ((size_t)h * SEQ + row) * DH;
    op[lane]      = acc0 * inv;
    op[lane + 64] = acc1 * inv;
}

extern "C" void kernel_launch(void* const* d_in, const int* in_sizes, int n_in,
                              void* d_out, int out_size, void* d_ws, size_t ws_size,
                              hipStream_t stream) {
    const float* Q        = (const float*)d_in[0];
    const float* K        = (const float*)d_in[1];
    const float* V        = (const float*)d_in[2];
    const float* ref_mask = (const float*)d_in[3];
    const float* routing  = (const float*)d_in[4];
    float* out = (float*)d_out;

    const size_t elems = (size_t)NH * SEQ * DH;
    const size_t need  = 2 * elems * sizeof(short);

    if (ws_size < need) {
        dim3 grid(SEQ / 4, NH);
        anystory_attn_scalar<<<grid, 256, 0, stream>>>(Q, K, V, ref_mask, routing, out, 0);
        return;
    }

    short* Kb  = (short*)d_ws;
    short* Vtg = Kb + elems;

    cvt_kv_kernel<<<dim3(SEQ / 16, NH), 256, 0, stream>>>(K, V, Kb, Vtg);

    // 26 block-cols per head (21 heavy, 1 router, 4 ref), head-major for XCD L2 locality
    attn_mfma<<<dim3(NH * 26), 256, 0, stream>>>(Q, Kb, Vtg, ref_mask, routing, out);
}